// Round 10
// baseline (223.824 us; speedup 1.0000x reference)
//
#include <hip/hip_runtime.h>
#include <hip/hip_bf16.h>
#include <cstdint>

#define B_ 8
#define C_ 256
#define N_ 4096

typedef __bf16 bf16;
typedef __bf16 bf16x8 __attribute__((ext_vector_type(8)));
typedef float f32x4 __attribute__((ext_vector_type(4)));
typedef unsigned int u32;

__device__ __forceinline__ void async_ld16(const void* g, void* l) {
  __builtin_amdgcn_global_load_lds(
      (const __attribute__((address_space(1))) void*)g,
      (__attribute__((address_space(3))) void*)l, 16, 0, 0);
}

__device__ __forceinline__ float bh2f(unsigned short u) {
  union { u32 i; float f; } x; x.i = ((u32)u) << 16; return x.f;
}
__device__ __forceinline__ unsigned short f2bh(float f) {
  union { float f; u32 i; } x; x.f = f;
  u32 i = x.i + 0x7fffu + ((x.i >> 16) & 1u);
  return (unsigned short)(i >> 16);
}

// Per-wave dtype sniff (fp32 vs bf16 buffer), validated R2/R3.
__device__ __forceinline__ bool wave_sniff_fp32(const unsigned short* p) {
  int l = threadIdx.x & 63;
  unsigned short u = p[2 * l];
  int e = (u >> 7) & 0xff;
  unsigned long long m = __ballot(e >= 112 && e <= 142);
  return __popcll(m) < 32;
}

// ---------------- kernel 0: Mt[d][c] = log2e * sum_e Wq[e][d]*Wk[e][c] ----------
// R22: also zeroes the 256 ticket counters (re-poison safety: counters must be
// reset every iteration; k_mt runs first in the chain).
__global__ __launch_bounds__(256) void k_mt(const void* __restrict__ Wqv,
                                            const void* __restrict__ Wkv,
                                            unsigned short* __restrict__ Mt,
                                            int* __restrict__ cnt) {
  __shared__ float wkcol[C_];
  int t = threadIdx.x;
  if (t == 0) cnt[blockIdx.x] = 0;  // 256 blocks = 256 counters
  bool fq = wave_sniff_fp32((const unsigned short*)Wqv);
  bool fk = wave_sniff_fp32((const unsigned short*)Wkv);
  int d = blockIdx.x, c = t;
  if (fk)
    wkcol[c] = ((const float*)Wkv)[c * C_ + d];
  else
    wkcol[c] = bh2f(((const unsigned short*)Wkv)[c * C_ + d]);
  __syncthreads();
  float acc = 0.f;
  if (fq) {
    for (int e0 = 0; e0 < C_; e0 += 16) {
      float wq[16];
#pragma unroll
      for (int j = 0; j < 16; ++j) wq[j] = ((const float*)Wqv)[(e0 + j) * C_ + c];
#pragma unroll
      for (int j = 0; j < 16; ++j) acc += wkcol[e0 + j] * wq[j];
    }
  } else {
    for (int e0 = 0; e0 < C_; e0 += 16) {
      float wq[16];
#pragma unroll
      for (int j = 0; j < 16; ++j) wq[j] = bh2f(((const unsigned short*)Wqv)[(e0 + j) * C_ + c]);
#pragma unroll
      for (int j = 0; j < 16; ++j) acc += wkcol[e0 + j] * wq[j];
    }
  }
  Mt[(size_t)d * C_ + c] = f2bh(acc * 1.44269504f);  // log2(e) fold (R18)
}

// ---------------- kernel 1: transpose F -> Ft AND G = Ft*Mt^T (fused, R9-exact) --
__global__ __launch_bounds__(256, 3) void k_tp(const void* __restrict__ Fv,
                                               const bf16* __restrict__ Mt,
                                               unsigned short* __restrict__ Ft,
                                               bf16* __restrict__ G) {
  __shared__ unsigned short tile[128 * 72];  // 18432 B; reused as Cs (needs 17408)
  __shared__ bf16 As[8 * 64 * 32];           // 32768 B; k_proj layout
  int n0 = blockIdx.x * 64;
  int b = blockIdx.y;
  int t = threadIdx.x;
  bool f32 = wave_sniff_fp32((const unsigned short*)Fv);

#pragma unroll
  for (int hp = 0; hp < 2; ++hp) {
    if (hp) __syncthreads();  // WAR: prior Phase-B tile reads complete
#pragma unroll
    for (int p = 0; p < 4; ++p) {
      int cl = (t >> 3) + 32 * p;
      int n8 = t & 7;
      size_t off = (size_t)(b * C_ + hp * 128 + cl) * N_ + n0 + n8 * 8;
      u32 o[4];
      if (f32) {
        const float* src = (const float*)Fv + off;
        float4 v0 = *(const float4*)(src);
        float4 v1 = *(const float4*)(src + 4);
        o[0] = ((u32)f2bh(v0.y) << 16) | f2bh(v0.x);
        o[1] = ((u32)f2bh(v0.w) << 16) | f2bh(v0.z);
        o[2] = ((u32)f2bh(v1.y) << 16) | f2bh(v1.x);
        o[3] = ((u32)f2bh(v1.w) << 16) | f2bh(v1.z);
      } else {
        uint4 v = *(const uint4*)((const unsigned short*)Fv + off);
        o[0] = v.x; o[1] = v.y; o[2] = v.z; o[3] = v.w;
      }
      uint4 ov; ov.x = o[0]; ov.y = o[1]; ov.z = o[2]; ov.w = o[3];
      int slot = (n8 + cl + (cl >> 3)) & 7;
      *(uint4*)(tile + cl * 72 + slot * 8) = ov;
    }
    __syncthreads();
#pragma unroll
    for (int p = 0; p < 2; ++p) {
      int flat = p * 256 + t;
      int np = flat >> 4, oc = flat & 15;
      int n = 2 * np, n8 = np >> 2, no = n & 7;
      u32 on0[4], on1[4];
#pragma unroll
      for (int k = 0; k < 4; ++k) {
        int row0 = oc * 8 + 2 * k, row1 = row0 + 1;
        int s0 = (n8 + row0 + oc) & 7;
        int s1 = (n8 + row1 + oc) & 7;
        u32 lo = *(const u32*)(tile + row0 * 72 + s0 * 8 + no);
        u32 hi = *(const u32*)(tile + row1 * 72 + s1 * 8 + no);
        on0[k] = ((hi & 0xffffu) << 16) | (lo & 0xffffu);
        on1[k] = (hi & 0xffff0000u) | (lo >> 16);
      }
      uint4 v0; v0.x = on0[0]; v0.y = on0[1]; v0.z = on0[2]; v0.w = on0[3];
      uint4 v1; v1.x = on1[0]; v1.y = on1[1]; v1.z = on1[2]; v1.w = on1[3];
      *(uint4*)(Ft + ((size_t)(b * N_ + n0 + n)) * C_ + hp * 128 + oc * 8) = v0;
      *(uint4*)(Ft + ((size_t)(b * N_ + n0 + n + 1)) * C_ + hp * 128 + oc * 8) = v1;
      int gc = hp * 16 + oc;
      int kc = gc >> 2, col8 = gc & 3, sw = np & 3;
      *(uint4*)((unsigned short*)As + kc * 2048 + n * 32 + (col8 ^ sw) * 8) = v0;
      *(uint4*)((unsigned short*)As + kc * 2048 + (n + 1) * 32 + (col8 ^ sw) * 8) = v1;
    }
  }
  __syncthreads();

  int w = t >> 6, l = t & 63, lr = l & 15, lq = l >> 4;
  int wn = w * 32;
  int rchunk = (lq ^ ((lr >> 1) & 3)) * 8;
  const size_t fbase = (size_t)b * N_ * C_;
#pragma unroll
  for (int jp = 0; jp < 2; ++jp) {
    int d0 = jp * 128;
    bf16x8 bb[2][8];
#pragma unroll
    for (int j = 0; j < 2; ++j)
#pragma unroll
      for (int kc = 0; kc < 8; ++kc)
        bb[j][kc] = *(const bf16x8*)(Mt + (size_t)(d0 + wn + 16 * j + lr) * C_ + kc * 32 + lq * 8);
    f32x4 acc[4][2] = {};
#pragma unroll
    for (int kc = 0; kc < 8; ++kc) {
#pragma unroll
      for (int i = 0; i < 4; ++i) {
        bf16x8 a = *(const bf16x8*)(As + kc * 2048 + (16 * i + lr) * 32 + rchunk);
#pragma unroll
        for (int j = 0; j < 2; ++j)
          acc[i][j] = __builtin_amdgcn_mfma_f32_16x16x32_bf16(a, bb[j][kc], acc[i][j], 0, 0, 0);
      }
    }
    __syncthreads();
    unsigned short* Cs = (unsigned short*)tile;
#pragma unroll
    for (int i = 0; i < 4; ++i)
#pragma unroll
      for (int j = 0; j < 2; ++j)
#pragma unroll
        for (int r = 0; r < 4; ++r)
          Cs[(16 * i + lq * 4 + r) * 136 + wn + 16 * j + lr] = f2bh(acc[i][j][r]);
    __syncthreads();
#pragma unroll
    for (int p = 0; p < 4; ++p) {
      int idx = p * 256 + t;
      int row = idx >> 4, c8 = idx & 15;
      uint4 v = *(const uint4*)(Cs + row * 136 + c8 * 8);
      *(uint4*)(G + fbase + (size_t)(n0 + row) * C_ + d0 + c8 * 8) = v;
    }
  }
}

// ---------------- kernel 2: attention + fused scale epilogue ---------------------
// Main loop = R7-exact (best measured 67.3-68.3us). R22: k_scale is FUSED as an
// atomic-ticket epilogue — the last of the 4 q-sibling blocks per (b,ntile)
// (device-scope atomicAdd ticket, threadfence release/acquire; counters zeroed
// by k_mt each iteration) computes the 128 dd divisors and scales its own
// 128n x 256c F-tile. Removes the k_scale launch + overlaps scale work with
// other tile-groups' attn tails. Arithmetic identical to the old k_scale.
__global__ __launch_bounds__(256, 4) void k_attn(const bf16* __restrict__ G,
                                                 const bf16* __restrict__ Ft,
                                                 float* __restrict__ snn,
                                                 float* __restrict__ lsum,
                                                 const void* __restrict__ Fv,
                                                 void* __restrict__ Outv,
                                                 int* __restrict__ cnt) {
  __shared__ bf16 Ks[2][32 * 256];  // 2 x 16 KB double buffer; chunk kc at kc*1024
  __shared__ int s_ticket;
  __shared__ __align__(16) float dd_lds[128];
  int bid = blockIdx.x;
  int b = bid & 7, q = (bid >> 3) & 3, ntile = bid >> 5;
  int n0 = ntile * 128;
  int t = threadIdx.x, w = t >> 6, l = t & 63;
  int lr = l & 15, lq = l >> 4;
  int wrow = w * 32;
  const size_t gbase = (size_t)b * N_ * C_;

  bf16x8 a[2][8];
#pragma unroll
  for (int i = 0; i < 2; ++i)
#pragma unroll
    for (int kc = 0; kc < 8; ++kc)
      a[i][kc] = *(const bf16x8*)(G + gbase + (size_t)(n0 + wrow + 16 * i + lr) * C_ + kc * 32 + lq * 8);

  float part[8];
#pragma unroll
  for (int s = 0; s < 8; ++s) part[s] = 0.f;

  int m_base = q * 1024;
  bool has_diag = (q == (ntile >> 3));
  int dbase = (ntile & 7) * 4;

  int soff[4];
#pragma unroll
  for (int p = 0; p < 4; ++p) {
    int flat = p * 256 + t;
    int kc = flat >> 7;
    int r = (flat >> 2) & 31;
    int col8 = flat & 3;
    soff[p] = r * C_ + kc * 32 + ((col8 ^ ((r >> 1) & 3)) * 8);
  }
  int rchunk = (lq ^ ((lr >> 1) & 3)) * 8;

#pragma unroll
  for (int p = 0; p < 4; ++p)
    async_ld16(Ft + gbase + (size_t)m_base * C_ + soff[p],
               (bf16*)Ks + (p * 256 + t) * 8);
  asm volatile("s_waitcnt vmcnt(0)" ::: "memory");
  __builtin_amdgcn_s_barrier();

  for (int it = 0; it < 32; ++it) {
    int cur = it & 1;
    if (it < 31) {
      int m0 = m_base + (it + 1) * 32;
#pragma unroll
      for (int p = 0; p < 4; ++p)
        async_ld16(Ft + gbase + (size_t)m0 * C_ + soff[p],
                   (bf16*)Ks + (cur ^ 1) * 8192 + (p * 256 + t) * 8);
    }
    const bf16* ks = (const bf16*)Ks + cur * 8192;
    f32x4 acc[2][2] = {};
#pragma unroll
    for (int kc = 0; kc < 8; ++kc) {
      bf16x8 b0 = *(const bf16x8*)(ks + kc * 1024 + lr * 32 + rchunk);
      bf16x8 b1 = *(const bf16x8*)(ks + kc * 1024 + (16 + lr) * 32 + rchunk);
      acc[0][0] = __builtin_amdgcn_mfma_f32_16x16x32_bf16(a[0][kc], b0, acc[0][0], 0, 0, 0);
      acc[1][0] = __builtin_amdgcn_mfma_f32_16x16x32_bf16(a[1][kc], b0, acc[1][0], 0, 0, 0);
      acc[0][1] = __builtin_amdgcn_mfma_f32_16x16x32_bf16(a[0][kc], b1, acc[0][1], 0, 0, 0);
      acc[1][1] = __builtin_amdgcn_mfma_f32_16x16x32_bf16(a[1][kc], b1, acc[1][1], 0, 0, 0);
    }
    bool dit = has_diag && ((it >> 2) == (ntile & 7));
#pragma unroll
    for (int i = 0; i < 2; ++i)
#pragma unroll
      for (int j = 0; j < 2; ++j)
#pragma unroll
        for (int r = 0; r < 4; ++r) {
          float e = __builtin_amdgcn_exp2f(acc[i][j][r]);  // logits carry log2e
          part[i * 4 + r] += e;
          if (dit) {
            int rloc = wrow + 16 * i + lq * 4 + r;
            int cloc = 16 * j + lr;
            if ((it - dbase) * 32 + cloc == rloc) snn[b * N_ + n0 + rloc] = e;
          }
        }
    if (it < 31) {
      asm volatile("s_waitcnt vmcnt(0)" ::: "memory");
      __builtin_amdgcn_s_barrier();
    }
  }

#pragma unroll
  for (int s = 0; s < 8; ++s) {
    float v = part[s];
    v += __shfl_xor(v, 1);
    v += __shfl_xor(v, 2);
    v += __shfl_xor(v, 4);
    v += __shfl_xor(v, 8);
    part[s] = v;
  }
  if (lr == 0) {
#pragma unroll
    for (int i = 0; i < 2; ++i)
#pragma unroll
      for (int r = 0; r < 4; ++r)
        lsum[((size_t)q * B_ + b) * N_ + n0 + wrow + 16 * i + lq * 4 + r] = part[i * 4 + r];
  }

  // ---- ticket epilogue: last q-sibling of (b,ntile) scales its 128n tile ----
  __syncthreads();  // all waves' snn/lsum stores issued (barrier drains vmcnt)
  if (t == 0) {
    __threadfence();  // release: make this block's stores device-visible
    s_ticket = atomicAdd(&cnt[ntile * 8 + b], 1);
  }
  __syncthreads();
  if (s_ticket != 3) return;
  __threadfence();  // acquire: siblings' snn/lsum now visible
  bool f32o = wave_sniff_fp32((const unsigned short*)Fv);
  if (t < 128) {
    int n = n0 + t;
    float s = snn[(size_t)b * N_ + n];
    float ls = 0.f;
#pragma unroll
    for (int p = 0; p < 4; ++p) ls += lsum[((size_t)p * B_ + b) * N_ + n];
    dd_lds[t] = s / (ls * (1.0f + 1e-8f));
  }
  __syncthreads();
  const size_t fb = (size_t)b * C_ * N_;
  if (f32o) {
    const float* F = (const float*)Fv;
    float* O = (float*)Outv;
#pragma unroll
    for (int p = 0; p < 32; ++p) {
      int idx = p * 256 + t;
      int c = idx >> 5, ch = idx & 31;  // 256 c x 32 float4-chunks of 128 n
      size_t off = fb + (size_t)c * N_ + n0 + ch * 4;
      float4 v = *(const float4*)(F + off);
      float4 d = *(const float4*)(&dd_lds[ch * 4]);
      float4 o;
      o.x = v.x * d.x; o.y = v.y * d.y; o.z = v.z * d.z; o.w = v.w * d.w;
      *(float4*)(O + off) = o;
    }
  } else {
    const unsigned short* F = (const unsigned short*)Fv;
    unsigned short* O = (unsigned short*)Outv;
#pragma unroll
    for (int p = 0; p < 16; ++p) {
      int idx = p * 256 + t;
      int c = idx >> 4, ch = idx & 15;  // 256 c x 16 uint4-chunks of 128 n
      size_t off = fb + (size_t)c * N_ + n0 + ch * 8;
      uint4 v = *(const uint4*)(F + off);
      u32 vv[4] = {v.x, v.y, v.z, v.w};
      u32 o[4];
#pragma unroll
      for (int k = 0; k < 4; ++k) {
        float lo = bh2f((unsigned short)(vv[k] & 0xffffu)) * dd_lds[ch * 8 + 2 * k];
        float hi = bh2f((unsigned short)(vv[k] >> 16)) * dd_lds[ch * 8 + 2 * k + 1];
        o[k] = ((u32)f2bh(hi) << 16) | f2bh(lo);
      }
      uint4 ov; ov.x = o[0]; ov.y = o[1]; ov.z = o[2]; ov.w = o[3];
      *(uint4*)(O + off) = ov;
    }
  }
}

extern "C" void kernel_launch(void* const* d_in, const int* in_sizes, int n_in,
                              void* d_out, int out_size, void* d_ws, size_t ws_size,
                              hipStream_t stream) {
  (void)in_sizes; (void)n_in; (void)out_size; (void)ws_size;
  const void* F = d_in[0];
  const void* Wq = d_in[1];
  const void* Wk = d_in[2];
  char* ws = (char*)d_ws;
  bf16* Ft = (bf16*)(ws);                         // 16 MiB
  bf16* G = (bf16*)(ws + (16u << 20));            // 16 MiB
  char* tail = ws + (32u << 20);
  float* snn = (float*)(tail);                    // 128 KiB
  float* lsum = (float*)(tail + 131072);          // 512 KiB (4 partials)
  bf16* Mt = (bf16*)(tail + 131072 + 524288);     // 128 KiB
  int* cnt = (int*)(tail + 131072 + 524288 + 131072);  // 1 KiB tickets

  k_mt<<<256, 256, 0, stream>>>(Wq, Wk, (unsigned short*)Mt, cnt);
  k_tp<<<dim3(N_ / 64, B_), 256, 0, stream>>>(F, Mt, (unsigned short*)Ft, G);
  k_attn<<<1024, 256, 0, stream>>>(G, Ft, snn, lsum, F, d_out, cnt);
}

// Round 11
// 167.713 us; speedup vs baseline: 1.3346x; 1.3346x over previous
//
#include <hip/hip_runtime.h>
#include <hip/hip_bf16.h>
#include <cstdint>

#define B_ 8
#define C_ 256
#define N_ 4096

typedef __bf16 bf16;
typedef __bf16 bf16x8 __attribute__((ext_vector_type(8)));
typedef float f32x4 __attribute__((ext_vector_type(4)));
typedef unsigned int u32;

__device__ __forceinline__ void async_ld16(const void* g, void* l) {
  __builtin_amdgcn_global_load_lds(
      (const __attribute__((address_space(1))) void*)g,
      (__attribute__((address_space(3))) void*)l, 16, 0, 0);
}

__device__ __forceinline__ float bh2f(unsigned short u) {
  union { u32 i; float f; } x; x.i = ((u32)u) << 16; return x.f;
}
__device__ __forceinline__ unsigned short f2bh(float f) {
  union { float f; u32 i; } x; x.f = f;
  u32 i = x.i + 0x7fffu + ((x.i >> 16) & 1u);
  return (unsigned short)(i >> 16);
}

// Per-wave dtype sniff (fp32 vs bf16 buffer), validated R2/R3.
__device__ __forceinline__ bool wave_sniff_fp32(const unsigned short* p) {
  int l = threadIdx.x & 63;
  unsigned short u = p[2 * l];
  int e = (u >> 7) & 0xff;
  unsigned long long m = __ballot(e >= 112 && e <= 142);
  return __popcll(m) < 32;
}

// ---------------- kernel 0: Mt[d][c] = log2e * sum_e Wq[e][d]*Wk[e][c] ----------
__global__ __launch_bounds__(256) void k_mt(const void* __restrict__ Wqv,
                                            const void* __restrict__ Wkv,
                                            unsigned short* __restrict__ Mt) {
  __shared__ float wkcol[C_];
  int t = threadIdx.x;
  bool fq = wave_sniff_fp32((const unsigned short*)Wqv);
  bool fk = wave_sniff_fp32((const unsigned short*)Wkv);
  int d = blockIdx.x, c = t;
  if (fk)
    wkcol[c] = ((const float*)Wkv)[c * C_ + d];
  else
    wkcol[c] = bh2f(((const unsigned short*)Wkv)[c * C_ + d]);
  __syncthreads();
  float acc = 0.f;
  if (fq) {
    for (int e0 = 0; e0 < C_; e0 += 16) {
      float wq[16];
#pragma unroll
      for (int j = 0; j < 16; ++j) wq[j] = ((const float*)Wqv)[(e0 + j) * C_ + c];
#pragma unroll
      for (int j = 0; j < 16; ++j) acc += wkcol[e0 + j] * wq[j];
    }
  } else {
    for (int e0 = 0; e0 < C_; e0 += 16) {
      float wq[16];
#pragma unroll
      for (int j = 0; j < 16; ++j) wq[j] = bh2f(((const unsigned short*)Wqv)[(e0 + j) * C_ + c]);
#pragma unroll
      for (int j = 0; j < 16; ++j) acc += wkcol[e0 + j] * wq[j];
    }
  }
  Mt[(size_t)d * C_ + c] = f2bh(acc * 1.44269504f);  // log2(e) fold (R18)
}

// ---------------- kernel 1: transpose F -> Ft AND G = Ft*Mt^T (fused, R9-exact) --
__global__ __launch_bounds__(256, 3) void k_tp(const void* __restrict__ Fv,
                                               const bf16* __restrict__ Mt,
                                               unsigned short* __restrict__ Ft,
                                               bf16* __restrict__ G) {
  __shared__ unsigned short tile[128 * 72];  // 18432 B; reused as Cs (needs 17408)
  __shared__ bf16 As[8 * 64 * 32];           // 32768 B; k_proj layout
  int n0 = blockIdx.x * 64;
  int b = blockIdx.y;
  int t = threadIdx.x;
  bool f32 = wave_sniff_fp32((const unsigned short*)Fv);

#pragma unroll
  for (int hp = 0; hp < 2; ++hp) {
    if (hp) __syncthreads();  // WAR: prior Phase-B tile reads complete
#pragma unroll
    for (int p = 0; p < 4; ++p) {
      int cl = (t >> 3) + 32 * p;
      int n8 = t & 7;
      size_t off = (size_t)(b * C_ + hp * 128 + cl) * N_ + n0 + n8 * 8;
      u32 o[4];
      if (f32) {
        const float* src = (const float*)Fv + off;
        float4 v0 = *(const float4*)(src);
        float4 v1 = *(const float4*)(src + 4);
        o[0] = ((u32)f2bh(v0.y) << 16) | f2bh(v0.x);
        o[1] = ((u32)f2bh(v0.w) << 16) | f2bh(v0.z);
        o[2] = ((u32)f2bh(v1.y) << 16) | f2bh(v1.x);
        o[3] = ((u32)f2bh(v1.w) << 16) | f2bh(v1.z);
      } else {
        uint4 v = *(const uint4*)((const unsigned short*)Fv + off);
        o[0] = v.x; o[1] = v.y; o[2] = v.z; o[3] = v.w;
      }
      uint4 ov; ov.x = o[0]; ov.y = o[1]; ov.z = o[2]; ov.w = o[3];
      int slot = (n8 + cl + (cl >> 3)) & 7;
      *(uint4*)(tile + cl * 72 + slot * 8) = ov;
    }
    __syncthreads();
#pragma unroll
    for (int p = 0; p < 2; ++p) {
      int flat = p * 256 + t;
      int np = flat >> 4, oc = flat & 15;
      int n = 2 * np, n8 = np >> 2, no = n & 7;
      u32 on0[4], on1[4];
#pragma unroll
      for (int k = 0; k < 4; ++k) {
        int row0 = oc * 8 + 2 * k, row1 = row0 + 1;
        int s0 = (n8 + row0 + oc) & 7;
        int s1 = (n8 + row1 + oc) & 7;
        u32 lo = *(const u32*)(tile + row0 * 72 + s0 * 8 + no);
        u32 hi = *(const u32*)(tile + row1 * 72 + s1 * 8 + no);
        on0[k] = ((hi & 0xffffu) << 16) | (lo & 0xffffu);
        on1[k] = (hi & 0xffff0000u) | (lo >> 16);
      }
      uint4 v0; v0.x = on0[0]; v0.y = on0[1]; v0.z = on0[2]; v0.w = on0[3];
      uint4 v1; v1.x = on1[0]; v1.y = on1[1]; v1.z = on1[2]; v1.w = on1[3];
      *(uint4*)(Ft + ((size_t)(b * N_ + n0 + n)) * C_ + hp * 128 + oc * 8) = v0;
      *(uint4*)(Ft + ((size_t)(b * N_ + n0 + n + 1)) * C_ + hp * 128 + oc * 8) = v1;
      int gc = hp * 16 + oc;
      int kc = gc >> 2, col8 = gc & 3, sw = np & 3;
      *(uint4*)((unsigned short*)As + kc * 2048 + n * 32 + (col8 ^ sw) * 8) = v0;
      *(uint4*)((unsigned short*)As + kc * 2048 + (n + 1) * 32 + (col8 ^ sw) * 8) = v1;
    }
  }
  __syncthreads();

  int w = t >> 6, l = t & 63, lr = l & 15, lq = l >> 4;
  int wn = w * 32;
  int rchunk = (lq ^ ((lr >> 1) & 3)) * 8;
  const size_t fbase = (size_t)b * N_ * C_;
#pragma unroll
  for (int jp = 0; jp < 2; ++jp) {
    int d0 = jp * 128;
    bf16x8 bb[2][8];
#pragma unroll
    for (int j = 0; j < 2; ++j)
#pragma unroll
      for (int kc = 0; kc < 8; ++kc)
        bb[j][kc] = *(const bf16x8*)(Mt + (size_t)(d0 + wn + 16 * j + lr) * C_ + kc * 32 + lq * 8);
    f32x4 acc[4][2] = {};
#pragma unroll
    for (int kc = 0; kc < 8; ++kc) {
#pragma unroll
      for (int i = 0; i < 4; ++i) {
        bf16x8 a = *(const bf16x8*)(As + kc * 2048 + (16 * i + lr) * 32 + rchunk);
#pragma unroll
        for (int j = 0; j < 2; ++j)
          acc[i][j] = __builtin_amdgcn_mfma_f32_16x16x32_bf16(a, bb[j][kc], acc[i][j], 0, 0, 0);
      }
    }
    __syncthreads();
    unsigned short* Cs = (unsigned short*)tile;
#pragma unroll
    for (int i = 0; i < 4; ++i)
#pragma unroll
      for (int j = 0; j < 2; ++j)
#pragma unroll
        for (int r = 0; r < 4; ++r)
          Cs[(16 * i + lq * 4 + r) * 136 + wn + 16 * j + lr] = f2bh(acc[i][j][r]);
    __syncthreads();
#pragma unroll
    for (int p = 0; p < 4; ++p) {
      int idx = p * 256 + t;
      int row = idx >> 4, c8 = idx & 15;
      uint4 v = *(const uint4*)(Cs + row * 136 + c8 * 8);
      *(uint4*)(G + fbase + (size_t)(n0 + row) * C_ + d0 + c8 * 8) = v;
    }
  }
}

// ---------------- kernel 2: attention row sums + diagonal ------------------------
// R23: rpw=64 in the untested cell {256-thr/4-wave blocks, 2 blocks/CU, 4-deep
// ring, counted vmcnt(8), setprio}. Each wave holds 64 n-rows (a[32]=128 regs);
// block covers 256 n-rows; grid 512 = exactly 2 blocks/CU (launch_bounds(256,2)
// caps regs at 256 architecturally). LDS-read traffic HALVES vs R7 (41us -> 20us
// pipe; it was the largest pipe above the 33us MFMA floor). Unlike R2 (drain-0
// convoy + regalloc mess) and R6 (1-block/CU 8-wave lockstep), this keeps
// cross-block overlap AND never-drain staging: ring of 4x16KB tiles, per-iter
// wait vmcnt(8) (tiles it+1,it+2 stay in flight), issue tile it+3 after the
// barrier (WAR-safe: readers of buf (it-1)&3 passed barrier(it)).
// Diag: has_diag = (q == ntile>>2); at it == (ntile&3)*8 + 2w + (i>>1),
// condition j==(i&1) && lr==lq*4+r (spot-checked n=1000 -> it=31,j=0,lr=8).
__global__ __launch_bounds__(256, 2) void k_attn(const bf16* __restrict__ G,
                                                 const bf16* __restrict__ Ft,
                                                 float* __restrict__ snn,
                                                 float* __restrict__ lsum) {
  __shared__ bf16 Ks[4][32 * 256];  // 4-deep ring, 16KB tiles; chunk kc at kc*1024
  int bid = blockIdx.x;
  int b = bid & 7, q = (bid >> 3) & 3, ntile = bid >> 5;  // ntile 0..15
  int n0 = ntile * 256;
  int t = threadIdx.x, w = t >> 6, l = t & 63;
  int lr = l & 15, lq = l >> 4;
  int wrow = w * 64;
  const size_t gbase = (size_t)b * N_ * C_;

  // A-frags: 64 rows x 256 k per wave = 32 x bf16x8 (128 regs)
  bf16x8 a[32];
#pragma unroll
  for (int i = 0; i < 4; ++i)
#pragma unroll
    for (int kc = 0; kc < 8; ++kc)
      a[i * 8 + kc] = *(const bf16x8*)(G + gbase + (size_t)(n0 + wrow + 16 * i + lr) * C_ + kc * 32 + lq * 8);

  float part[16];
#pragma unroll
  for (int s = 0; s < 16; ++s) part[s] = 0.f;

  int m_base = q * 1024;
  bool has_diag = (q == (ntile >> 2));
  int dbase = (ntile & 3) * 8;

  // staging offsets: 4 x 16B per thread per 32-row tile (16KB = 1024 x 16B)
  int soff[4];
#pragma unroll
  for (int p = 0; p < 4; ++p) {
    int flat = p * 256 + t;
    int kc = flat >> 7;
    int r = (flat >> 2) & 31;
    int col8 = flat & 3;
    soff[p] = r * C_ + kc * 32 + ((col8 ^ ((r >> 1) & 3)) * 8);
  }
  int rchunk = (lq ^ ((lr >> 1) & 3)) * 8;

  // prologue: issue tiles 0,1,2 (12 loads/thread in flight)
#pragma unroll
  for (int s = 0; s < 3; ++s)
#pragma unroll
    for (int p = 0; p < 4; ++p)
      async_ld16(Ft + gbase + (size_t)(m_base + s * 32) * C_ + soff[p],
                 (bf16*)Ks + s * 8192 + (p * 256 + t) * 8);

  for (int it = 0; it < 32; ++it) {
    // wait for tile it; keep tiles it+1, it+2 (8 loads) in flight
    if (it <= 29) {
      asm volatile("s_waitcnt vmcnt(8)" ::: "memory");
    } else if (it == 30) {
      asm volatile("s_waitcnt vmcnt(4)" ::: "memory");
    } else {
      asm volatile("s_waitcnt vmcnt(0)" ::: "memory");
    }
    __builtin_amdgcn_s_barrier();
    // issue tile it+3 AFTER the barrier (WAR-safe vs readers of buf (it-1)&3)
    if (it <= 28) {
      int m0 = m_base + (it + 3) * 32;
      bf16* dst = (bf16*)Ks + ((it + 3) & 3) * 8192;
#pragma unroll
      for (int p = 0; p < 4; ++p)
        async_ld16(Ft + gbase + (size_t)m0 * C_ + soff[p], dst + (p * 256 + t) * 8);
    }

    const bf16* ks = (const bf16*)Ks + (it & 3) * 8192;
    f32x4 acc[8] = {};  // [i*2+j]
    __builtin_amdgcn_s_setprio(1);
#pragma unroll
    for (int kc = 0; kc < 8; ++kc) {
      bf16x8 b0 = *(const bf16x8*)(ks + kc * 1024 + lr * 32 + rchunk);
      bf16x8 b1 = *(const bf16x8*)(ks + kc * 1024 + (16 + lr) * 32 + rchunk);
#pragma unroll
      for (int i = 0; i < 4; ++i) {
        acc[i * 2 + 0] = __builtin_amdgcn_mfma_f32_16x16x32_bf16(a[i * 8 + kc], b0, acc[i * 2 + 0], 0, 0, 0);
        acc[i * 2 + 1] = __builtin_amdgcn_mfma_f32_16x16x32_bf16(a[i * 8 + kc], b1, acc[i * 2 + 1], 0, 0, 0);
      }
    }
    __builtin_amdgcn_s_setprio(0);

#pragma unroll
    for (int i = 0; i < 4; ++i) {
      bool dit = has_diag && (it == dbase + 2 * w + (i >> 1));
#pragma unroll
      for (int j = 0; j < 2; ++j)
#pragma unroll
        for (int r = 0; r < 4; ++r) {
          float e = __builtin_amdgcn_exp2f(acc[i * 2 + j][r]);  // logits carry log2e
          part[i * 4 + r] += e;
          if (dit && j == (i & 1) && lr == lq * 4 + r)
            snn[b * N_ + n0 + wrow + 16 * i + lq * 4 + r] = e;
        }
    }
  }

#pragma unroll
  for (int s = 0; s < 16; ++s) {
    float v = part[s];
    v += __shfl_xor(v, 1);
    v += __shfl_xor(v, 2);
    v += __shfl_xor(v, 4);
    v += __shfl_xor(v, 8);
    part[s] = v;
  }
  if (lr == 0) {
#pragma unroll
    for (int i = 0; i < 4; ++i)
#pragma unroll
      for (int r = 0; r < 4; ++r)
        lsum[((size_t)q * B_ + b) * N_ + n0 + wrow + 16 * i + lq * 4 + r] = part[i * 4 + r];
  }
}

// ---------------- kernel 3: out = F * snn/(sum_q lsum * (1+1e-8)) ----------------
// R7-exact (best-measured total config): 512 blocks, 64 dd[n] divisors once per
// block into LDS, F/out streaming coalesced.
__global__ __launch_bounds__(256) void k_scale(const void* __restrict__ Fv,
                                               const float* __restrict__ snn,
                                               const float* __restrict__ lsum,
                                               void* __restrict__ Outv) {
  __shared__ __align__(16) float dd_lds[64];
  bool f32 = wave_sniff_fp32((const unsigned short*)Fv);
  int bid = blockIdx.x;
  int b = bid >> 6, n0 = (bid & 63) * 64;
  int t = threadIdx.x;
  if (t < 64) {
    int n = n0 + t;
    float s = snn[(size_t)b * N_ + n];
    float ls = 0.f;
#pragma unroll
    for (int p = 0; p < 4; ++p) ls += lsum[((size_t)p * B_ + b) * N_ + n];
    dd_lds[t] = s / (ls * (1.0f + 1e-8f));
  }
  __syncthreads();
  const size_t fb = (size_t)b * C_ * N_;
  if (f32) {
    const float* F = (const float*)Fv;
    float* O = (float*)Outv;
#pragma unroll
    for (int p = 0; p < 16; ++p) {
      int idx = p * 256 + t;
      int c = idx >> 4, ch = idx & 15;
      size_t off = fb + (size_t)c * N_ + n0 + ch * 4;
      float4 v = *(const float4*)(F + off);
      float4 d = *(const float4*)(&dd_lds[ch * 4]);
      float4 o;
      o.x = v.x * d.x; o.y = v.y * d.y; o.z = v.z * d.z; o.w = v.w * d.w;
      *(float4*)(O + off) = o;
    }
  } else {
    const unsigned short* F = (const unsigned short*)Fv;
    unsigned short* O = (unsigned short*)Outv;
#pragma unroll
    for (int p = 0; p < 8; ++p) {
      int idx = p * 256 + t;
      int c = idx >> 3, ch = idx & 7;
      size_t off = fb + (size_t)c * N_ + n0 + ch * 8;
      uint4 v = *(const uint4*)(F + off);
      u32 vv[4] = {v.x, v.y, v.z, v.w};
      u32 o[4];
#pragma unroll
      for (int k = 0; k < 4; ++k) {
        float lo = bh2f((unsigned short)(vv[k] & 0xffffu)) * dd_lds[ch * 8 + 2 * k];
        float hi = bh2f((unsigned short)(vv[k] >> 16)) * dd_lds[ch * 8 + 2 * k + 1];
        o[k] = ((u32)f2bh(hi) << 16) | f2bh(lo);
      }
      uint4 ov; ov.x = o[0]; ov.y = o[1]; ov.z = o[2]; ov.w = o[3];
      *(uint4*)(O + off) = ov;
    }
  }
}

extern "C" void kernel_launch(void* const* d_in, const int* in_sizes, int n_in,
                              void* d_out, int out_size, void* d_ws, size_t ws_size,
                              hipStream_t stream) {
  (void)in_sizes; (void)n_in; (void)out_size; (void)ws_size;
  const void* F = d_in[0];
  const void* Wq = d_in[1];
  const void* Wk = d_in[2];
  char* ws = (char*)d_ws;
  bf16* Ft = (bf16*)(ws);                         // 16 MiB
  bf16* G = (bf16*)(ws + (16u << 20));            // 16 MiB
  char* tail = ws + (32u << 20);
  float* snn = (float*)(tail);                    // 128 KiB
  float* lsum = (float*)(tail + 131072);          // 512 KiB (4 partials)
  bf16* Mt = (bf16*)(tail + 131072 + 524288);     // 128 KiB

  k_mt<<<256, 256, 0, stream>>>(Wq, Wk, (unsigned short*)Mt);
  k_tp<<<dim3(N_ / 64, B_), 256, 0, stream>>>(F, Mt, (unsigned short*)Ft, G);
  k_attn<<<512, 256, 0, stream>>>(G, Ft, snn, lsum);
  k_scale<<<512, 256, 0, stream>>>(F, snn, lsum, d_out);
}